// Round 14
// baseline (139.527 us; speedup 1.0000x reference)
//
#include <hip/hip_runtime.h>
#include <cmath>

typedef float f4 __attribute__((ext_vector_type(4)));
typedef float f32x4 __attribute__((ext_vector_type(4)));
typedef short bf16x8 __attribute__((ext_vector_type(8)));
typedef unsigned short u16x8 __attribute__((ext_vector_type(8)));
typedef unsigned int u32x4 __attribute__((ext_vector_type(4)));

#define SCALEF 8.0f   // alpha/rank = 32/4

__device__ __forceinline__ unsigned cvtpk(float lo, float hi) {
    unsigned r;
    asm("v_cvt_pk_bf16_f32 %0, %1, %2" : "=v"(r) : "v"(lo), "v"(hi));
    return r;
}
__device__ __forceinline__ bf16x8 packA(const f4 a, const f4 b) {
    u32x4 u;
    u[0] = cvtpk(a[0], a[1]);
    u[1] = cvtpk(a[2], a[3]);
    u[2] = cvtpk(b[0], b[1]);
    u[3] = cvtpk(b[2], b[3]);
    return __builtin_bit_cast(bf16x8, u);
}

// ---- k0: prepack 12 weight rows into MFMA B-fragment stream (bf16) -------
__global__ __launch_bounds__(256, 4) void k0_pack(
    const float* __restrict__ A_w,
    const float* __restrict__ router_w,
    unsigned short* __restrict__ wq)
{
    const int idx = blockIdx.x * 256 + threadIdx.x;   // 0..8191
    const int l = idx & 63, s = idx >> 6;
    const int w = l & 15;
    const int kb = 32 * s + (l >> 4) * 8;
    u16x8 o = (u16x8)0;
    if (w < 12) {
        const float* __restrict__ row = (w < 8)
            ? router_w + (size_t)w * 4096
            : A_w + (size_t)(w - 8) * 4096;
#pragma unroll
        for (int j = 0; j < 8; ++j) {
            union { float f; unsigned u; } a;
            a.f = row[kb + j];
            o[j] = (unsigned short)((a.u + 0x7FFFu + ((a.u >> 16) & 1u)) >> 16);
        }
    }
    *((u16x8*)wq + idx) = o;
}

struct Banks2 { f4 a0[2], a1[2]; u16x8 wb[2]; };
__device__ __forceinline__ void load2(Banks2& B, const f4* __restrict__ xr,
                                      const u16x8* __restrict__ wr, int sb) {
#pragma unroll
    for (int i = 0; i < 2; ++i) {
        B.a0[i] = xr[8 * (sb + i)];
        B.a1[i] = xr[8 * (sb + i) + 1];
        B.wb[i] = wr[(sb + i) << 6];
    }
}
__device__ __forceinline__ void mfma2(f32x4& acc, const Banks2& B) {
#pragma unroll
    for (int i = 0; i < 2; ++i)
        acc = __builtin_amdgcn_mfma_f32_16x16x32_bf16(
            packA(B.a0[i], B.a1[i]), __builtin_bit_cast(bf16x8, B.wb[i]),
            acc, 0, 0, 0);
}

// ---- k1: read streamer. 2048 blocks = 1024 tiles x 2 K-halves. -----------
// Wave = 16 K-steps; block reduce; writes [tile*2+kh][16 tok][12] partials.
__global__ __launch_bounds__(256, 6) void k1_mfma(
    const float* __restrict__ x,
    const unsigned short* __restrict__ wq,
    float* __restrict__ s12p)
{
    const int tid  = threadIdx.x;
    const int wid  = tid >> 6, lane = tid & 63;
    const int tile = blockIdx.x >> 1, kh = blockIdx.x & 1;
    const int tok0 = tile * 16;
    const int s0   = kh * 64 + wid * 16;      // K-step base (steps of 32 k)

    const f4* __restrict__ xr =
        (const f4*)x + ((size_t)(tok0 + (lane & 15)) << 10) + ((lane >> 4) << 1);
    const u16x8* __restrict__ wr = (const u16x8*)wq + lane;

    Banks2 A, C;
    load2(A, xr, wr, s0);
    load2(C, xr, wr, s0 + 2);
    f32x4 acc = {0.f, 0.f, 0.f, 0.f};

    mfma2(acc, A); load2(A, xr, wr, s0 + 4);
    mfma2(acc, C); load2(C, xr, wr, s0 + 6);
    mfma2(acc, A); load2(A, xr, wr, s0 + 8);
    mfma2(acc, C); load2(C, xr, wr, s0 + 10);
    mfma2(acc, A); load2(A, xr, wr, s0 + 12);
    mfma2(acc, C); load2(C, xr, wr, s0 + 14);
    mfma2(acc, A);
    mfma2(acc, C);

    // C layout: lane holds scores[token=(lane>>4)*4+r][weight=lane&15]
    __shared__ float red[4][16][17];
#pragma unroll
    for (int r = 0; r < 4; ++r)
        red[wid][(lane >> 4) * 4 + r][lane & 15] = acc[r];
    __syncthreads();   // all K-loop loads consumed -> drain is free

    if (tid < 16) {
        float* __restrict__ dst =
            s12p + ((size_t)(tile * 2 + kh) * 16 + tid) * 12;
#pragma unroll
        for (int g = 0; g < 3; ++g) {
            f4 s;
#pragma unroll
            for (int j = 0; j < 4; ++j)
                s[j] = red[0][tid][4 * g + j] + red[1][tid][4 * g + j] +
                       red[2][tid][4 * g + j] + red[3][tid][4 * g + j];
            *(f4*)(dst + 4 * g) = s;   // 48B row stride, 16B aligned
        }
    }
}

// ---- k2: write streamer. 16384 blocks = 4096 token-quads x 4 col-quarters.
__global__ __launch_bounds__(256, 8) void k2_store(
    const float* __restrict__ s12p,
    const float* __restrict__ B_w,
    const float* __restrict__ expert_vectors,
    float* __restrict__ out)
{
    const int tid  = threadIdx.x;
    const int tq   = blockIdx.x >> 2;     // token quad 0..4095
    const int cq   = blockIdx.x & 3;      // column quarter
    const int tile = tq >> 2;
    const int hi   = tq & 3;              // sub-quad within tile

    // epilogue per token (redundant across threads; all loads L1-broadcast)
    f4 h[4];
#pragma unroll
    for (int r = 0; r < 4; ++r) {
        const float* __restrict__ pa =
            s12p + ((size_t)(tile * 2 + 0) * 16 + hi * 4 + r) * 12;
        const float* __restrict__ pb =
            s12p + ((size_t)(tile * 2 + 1) * 16 + hi * 4 + r) * 12;
        float s12[12];
#pragma unroll
        for (int g = 0; g < 3; ++g) {
            const f4 a = *(const f4*)(pa + 4 * g);
            const f4 b = *(const f4*)(pb + 4 * g);
#pragma unroll
            for (int j = 0; j < 4; ++j) s12[4 * g + j] = a[j] + b[j];
        }
        int   idx[4];
        float val[4];
#pragma unroll
        for (int k = 0; k < 4; ++k) {
            int bi = 0; float bv = s12[0];
#pragma unroll
            for (int e = 1; e < 8; ++e)
                if (s12[e] > bv) { bv = s12[e]; bi = e; }
            idx[k] = bi; val[k] = bv;
#pragma unroll
            for (int e = 0; e < 8; ++e)
                if (e == bi) s12[e] = -INFINITY;   // static-index knockout
        }
        float ex[4], se = 0.f;
#pragma unroll
        for (int k = 0; k < 4; ++k) { ex[k] = expf(val[k] - val[0]); se += ex[k]; }
        const float inv = 1.f / se;
        float Et[4] = {0.f, 0.f, 0.f, 0.f};
#pragma unroll
        for (int k = 0; k < 4; ++k) {
            const float wgt = ex[k] * inv;
#pragma unroll
            for (int r2 = 0; r2 < 4; ++r2)
                Et[r2] = fmaf(wgt, expert_vectors[idx[k] * 4 + r2], Et[r2]);
        }
#pragma unroll
        for (int r2 = 0; r2 < 4; ++r2) {
            const float hv = s12[8 + r2] + Et[r2];
            h[r][r2] = SCALEF * 0.5f * hv *
                       (1.f + erff(hv * 0.70710678118654752f));
        }
    }

    // store phase: 4 tokens x 16B/thread, B_w from L1/L2
    const int c = cq * 256 + tid;
    const f4* __restrict__ b4 = (const f4*)B_w;
    const f4 B0 = b4[4 * c + 0], B1 = b4[4 * c + 1],
             B2 = b4[4 * c + 2], B3 = b4[4 * c + 3];
#pragma unroll
    for (int t = 0; t < 4; ++t) {
        const f4 hh = h[t];
        f4 v;
        v[0] = B0[0] * hh[0] + B0[1] * hh[1] + B0[2] * hh[2] + B0[3] * hh[3];
        v[1] = B1[0] * hh[0] + B1[1] * hh[1] + B1[2] * hh[2] + B1[3] * hh[3];
        v[2] = B2[0] * hh[0] + B2[1] * hh[1] + B2[2] * hh[2] + B2[3] * hh[3];
        v[3] = B3[0] * hh[0] + B3[1] * hh[1] + B3[2] * hh[2] + B3[3] * hh[3];
        __builtin_nontemporal_store(
            v, (f4*)out + (size_t)(tq * 4 + t) * 1024 + c);
    }
}

extern "C" void kernel_launch(void* const* d_in, const int* in_sizes, int n_in,
                              void* d_out, int out_size, void* d_ws, size_t ws_size,
                              hipStream_t stream) {
    const float* x        = (const float*)d_in[0];
    const float* A_w      = (const float*)d_in[1];
    const float* B_w      = (const float*)d_in[2];
    const float* router_w = (const float*)d_in[3];
    const float* ev       = (const float*)d_in[4];
    float* out            = (float*)d_out;

    unsigned short* wq = (unsigned short*)d_ws;               // 128 KB
    float* s12p        = (float*)((char*)d_ws + 131072);      // 1.5 MB

    k0_pack <<<32,    256, 0, stream>>>(A_w, router_w, wq);
    k1_mfma <<<2048,  256, 0, stream>>>(x, wq, s12p);
    k2_store<<<16384, 256, 0, stream>>>(s12p, B_w, ev, out);
}